// Round 12
// baseline (26414.325 us; speedup 1.0000x reference)
//
#include <hip/hip_runtime.h>

#define Bb  128
#define Tt  512
#define Ff  512
#define Hh  1024
#define BH  (Bb*Hh)
#define WGS 512
#define NBLK 256
#define NPH 513

#define OFF_H1   0u
#define OFF_H2   524288u
#define OFF_H2F  1048576u
#define OFF_BAR  1572864u
#define OFF_XB   1576960u
#define WS_NEED  (1576960u + 67108864u)

typedef __attribute__((ext_vector_type(8))) short short8;
typedef __attribute__((ext_vector_type(4))) float f32x4;
typedef __attribute__((ext_vector_type(16))) float f32x16;

__device__ __forceinline__ short f2bf(float f){
  union { float fv; unsigned u; } v; v.fv = f;
  unsigned r = v.u + 0x7fffu + ((v.u >> 16) & 1u);   // RNE
  return (short)(r >> 16);
}
__device__ __forceinline__ float sigm(float x){ return 1.f/(1.f+__expf(-x)); }

__device__ __forceinline__ f32x16 mfma32(short8 a, short8 b, f32x16 c){
  return __builtin_amdgcn_mfma_f32_32x32x16_bf16(a, b, c, 0, 0, 0);
}

// system-scope (MALL) ops — R5/R8-proven coherence for cross-XCD h state
__device__ __forceinline__ short8 scld8(const short* p){
  short8 d;
  asm volatile("global_load_dwordx4 %0, %1, off sc0 sc1" : "=v"(d) : "v"(p) : "memory");
  return d;
}
__device__ __forceinline__ void ssth(short* p, short v){
  asm volatile("global_store_short %0, %1, off sc0 sc1"
               :: "v"(p), "v"((unsigned)(unsigned short)v) : "memory");
}
__device__ __forceinline__ void drain_vm(){
  asm volatile("s_waitcnt vmcnt(0)" ::: "memory");
  __builtin_amdgcn_sched_barrier(0);
}

__global__ void __launch_bounds__(WGS) conv_x(const float* __restrict__ xf,
                                              short* __restrict__ xb){
  const size_t i = ((size_t)blockIdx.x * WGS + threadIdx.x) * 8;
  float4 u0 = *(const float4*)(xf + i);
  float4 u1 = *(const float4*)(xf + i + 4);
  short8 v;
  v[0]=f2bf(u0.x); v[1]=f2bf(u0.y); v[2]=f2bf(u0.z); v[3]=f2bf(u0.w);
  v[4]=f2bf(u1.x); v[5]=f2bf(u1.y); v[6]=f2bf(u1.z); v[7]=f2bf(u1.w);
  *(short8*)(xb + i) = v;
}

// R12: NO partial exchange. grp = bid>>7: 0 = layer-1 (x@Wih1 + h1@Whh1),
// 1 = layer-2 (h1@Wih2 + h2@Whh2). Per CU: 64 rows x 16 h-cols; 8 waves =
// cth(2) x kseg(4); per-wave B-weights (one 512-K segment) in registers.
// Phase p: grp0 computes step p (p<512); grp1 computes step p-1 (p>=1).
// Staging: 64KB chunks [64 rows][512 K] via R8's strict issue/drain/write/sync.
__global__ void __launch_bounds__(WGS, 1) lstm2(
    const short* __restrict__ xb,
    const float* __restrict__ Wih1, const float* __restrict__ Whh1,
    const float* __restrict__ bih1, const float* __restrict__ bhh1,
    const float* __restrict__ Wih2, const float* __restrict__ Whh2,
    const float* __restrict__ bih2, const float* __restrict__ bhh2,
    short* __restrict__ h1, short* __restrict__ h2,
    float* __restrict__ h2f32, unsigned* __restrict__ bar)
{
  extern __shared__ char lds[];
  // stage dbuf: 2 x 64KB chunks; F [4 kseg][64 rows][64 fragcols] f32 (64KB)
  // aliases buf0 region AFTER the last chunk's compute (sync-separated).
  float* F  = (float*)lds;
  float* Lb = (float*)(lds + 131072);    // 64 f32 bias sums

  const int bid = blockIdx.x, tid = threadIdx.x;
  const int grp   = bid >> 7;
  const int sub   = bid & 127;
  const int rbase = (sub >> 6) << 6;     // 0 or 64
  const int c0h   = (sub & 63) << 4;     // 16 h-cols per CU
  const int lane = tid & 63, wv = tid >> 6;
  const int tc = lane & 31, hi = lane >> 5;
  const int cth = wv & 1, kseg = wv >> 1;
  const int slot = bid & 7;
  const int nch  = grp ? 4 : 3;          // chunks per phase

  if (tid < 64){
    const int hc = tid >> 2, g = tid & 3;
    Lb[tid] = grp ? bih2[(g<<10)+c0h+hc] + bhh2[(g<<10)+c0h+hc]
                  : bih1[(g<<10)+c0h+hc] + bhh1[(g<<10)+c0h+hc];
  }

  // ---- per-wave weights into registers (fp32 -> bf16), once ----
  // grp0: kseg 0,1 = Whh1 K-halves; kseg 2 = Wih1 (K=512); kseg 3 idle.
  // grp1: kseg 0,1 = Wih2 K-halves; kseg 2,3 = Whh2 K-halves.
  short8 bfr[32];
  {
    const float* Wsrc = nullptr; int Kdim = 1024, kb0 = 0;
    if (grp == 0){
      if (kseg < 2){ Wsrc = Whh1; kb0 = kseg << 9; }
      else if (kseg == 2){ Wsrc = Wih1; Kdim = 512; }
    } else {
      if (kseg < 2){ Wsrc = Wih2; kb0 = kseg << 9; }
      else { Wsrc = Whh2; kb0 = (kseg - 2) << 9; }
    }
    const int wrow = (tc&3)*Hh + c0h + cth*8 + (tc>>2);   // gate-interleaved
    if (Wsrc){
      const float* wb = Wsrc + (size_t)wrow*Kdim + kb0 + (hi<<3);
      #pragma unroll
      for (int f = 0; f < 32; ++f){
        float4 u0 = *(const float4*)(wb + (f<<4));
        float4 u1 = *(const float4*)(wb + (f<<4) + 4);
        short8 v;
        v[0]=f2bf(u0.x); v[1]=f2bf(u0.y); v[2]=f2bf(u0.z); v[3]=f2bf(u0.w);
        v[4]=f2bf(u1.x); v[5]=f2bf(u1.y); v[6]=f2bf(u1.z); v[7]=f2bf(u1.w);
        bfr[f] = v;
      }
    } else {
      #pragma unroll
      for (int f = 0; f < 32; ++f) bfr[f] = short8{0,0,0,0,0,0,0,0};
    }
  }
  __syncthreads();

  float cst[2] = {0.f, 0.f};

  for (int p = 0; p < NPH; ++p){
    const bool act = grp ? (p >= 1) : (p < Tt);

    f32x16 a0, a1;
    #pragma unroll
    for (int i = 0; i < 16; ++i){ a0[i] = 0.f; a1[i] = 0.f; }

    // ---- chunks: stage (issue/drain/write/sync) then compute (owner kseg) ----
    for (int r = 0; r < nch; ++r){
      if (act){
        short8 t[8];
        if (grp == 0 && r == 2){
          #pragma unroll
          for (int i = 0; i < 8; ++i){
            const int u = (i<<9)+tid, row = u>>6, g = u&63;
            t[i] = *(const short8*)(xb + ((size_t)(rbase+row)*Tt + p)*Ff + (g<<3));
          }
        } else {
          const short* hp; int ko;
          if (r < 2){ hp = h1 + ((p+1)&1)*BH; ko = r<<9; }
          else      { hp = h2 + (p&1)*BH;     ko = (r-2)<<9; }
          #pragma unroll
          for (int i = 0; i < 8; ++i){
            const int u = (i<<9)+tid, row = u>>6, g = u&63;
            t[i] = scld8(hp + (size_t)(rbase+row)*Hh + ko + (g<<3));
          }
        }
        drain_vm();
        char* dst = lds + (r&1)*65536;
        #pragma unroll
        for (int i = 0; i < 8; ++i){
          const int u = (i<<9)+tid, row = u>>6, g = u&63;
          *(short8*)(dst + (row<<10) + (((g ^ row)&63)<<4)) = t[i];
        }
      }
      __syncthreads();                   // chunk r staged
      if (act && kseg == r){
        const char* base = lds + (r&1)*65536;
        const int r0 = tc, r1 = 32+tc;
        #pragma unroll
        for (int ci = 0; ci < 32; ++ci){
          const int g0 = (ci<<1) | hi;
          a0 = mfma32(*(const short8*)(base + (r0<<10) + (((g0 ^ r0)&63)<<4)), bfr[ci], a0);
          a1 = mfma32(*(const short8*)(base + (r1<<10) + (((g0 ^ r1)&63)<<4)), bfr[ci], a1);
        }
      }
      __syncthreads();                   // chunk r reads done, buf reusable
    }

    // ---- dump kseg partials: F[kseg][64 rows][64 fragcols] ----
    if (act && (grp == 1 || kseg < 3)){
      const int colf = (cth<<5) + tc;
      #pragma unroll
      for (int rg = 0; rg < 16; ++rg){
        const int rl = (rg&3) + ((rg>>2)<<3) + (hi<<2);
        F[(kseg<<12) + (rl<<6) + colf]      = a0[rg];
        F[(kseg<<12) + ((32+rl)<<6) + colf] = a1[rg];
      }
    }
    __syncthreads();                     // F complete

    // ---- update: sum ksegs, bias, LSTM cell, write h ----
    if (act){
      #pragma unroll
      for (int s = 0; s < 2; ++s){
        const int id = (s<<9)+tid, row = id>>4, hc = id&15;
        f32x4 q = *(f32x4*)&F[(row<<6) + (hc<<2)];
        q += *(f32x4*)&F[4096 + (row<<6) + (hc<<2)];
        q += *(f32x4*)&F[8192 + (row<<6) + (hc<<2)];
        if (grp) q += *(f32x4*)&F[12288 + (row<<6) + (hc<<2)];
        f32x4 bb = *(f32x4*)&Lb[hc<<2];
        float gi=q[0]+bb[0], gf=q[1]+bb[1], gg=q[2]+bb[2], go=q[3]+bb[3];
        float iv=sigm(gi), fv=sigm(gf), gv=tanhf(gg), ov=sigm(go);
        cst[s] = fv*cst[s] + iv*gv;
        float hv = ov*tanhf(cst[s]);
        if (grp == 0){                   // step p -> h1[p]
          ssth(h1 + (p&1)*BH + (size_t)(rbase+row)*Hh + c0h + hc, f2bf(hv));
        } else {                         // step p-1 -> h2[p-1]
          ssth(h2 + ((p+1)&1)*BH + (size_t)(rbase+row)*Hh + c0h + hc, f2bf(hv));
          if (p == Tt) h2f32[(size_t)(rbase+row)*Hh + c0h + hc] = hv;
        }
      }
    }

    // ---- two-level relaxed grid barrier (syncthreads drains sc-stores) ----
    __syncthreads();
    if (tid == 0){
      unsigned prev = __hip_atomic_fetch_add(bar + (slot<<6), 1u,
                        __ATOMIC_RELAXED, __HIP_MEMORY_SCOPE_AGENT);
      if (prev == 32u*(p+1) - 1u)
        __hip_atomic_fetch_add(bar + 768, 1u,
                        __ATOMIC_RELAXED, __HIP_MEMORY_SCOPE_AGENT);
      while (__hip_atomic_load(bar + 768,
                        __ATOMIC_RELAXED, __HIP_MEMORY_SCOPE_AGENT) < 8u*(p+1))
        __builtin_amdgcn_s_sleep(1);
    }
    __syncthreads();
  }
}

__global__ void final_linear(const float* __restrict__ h2, const float* __restrict__ Wl,
                             const float* __restrict__ bl, float* __restrict__ out){
  __shared__ float red[256];
  const int b = blockIdx.x, t = threadIdx.x;
  float s = 0.f;
  for (int k = t; k < Hh; k += 256) s += h2[(size_t)b*Hh + k] * Wl[k];
  red[t] = s; __syncthreads();
  for (int off = 128; off > 0; off >>= 1){ if (t < off) red[t] += red[t+off]; __syncthreads(); }
  if (t == 0) out[b] = red[0] + bl[0];
}

extern "C" void kernel_launch(void* const* d_in, const int* in_sizes, int n_in,
                              void* d_out, int out_size, void* d_ws, size_t ws_size,
                              hipStream_t stream) {
  (void)in_sizes; (void)n_in; (void)out_size;
  const float* x    = (const float*)d_in[0];
  const float* Wih1 = (const float*)d_in[1];
  const float* Whh1 = (const float*)d_in[2];
  const float* bih1 = (const float*)d_in[3];
  const float* bhh1 = (const float*)d_in[4];
  const float* Wih2 = (const float*)d_in[5];
  const float* Whh2 = (const float*)d_in[6];
  const float* bih2 = (const float*)d_in[7];
  const float* bhh2 = (const float*)d_in[8];
  const float* Wlin = (const float*)d_in[9];
  const float* blin = (const float*)d_in[10];
  float* out = (float*)d_out;

  if (ws_size < WS_NEED) return;
  char* ws = (char*)d_ws;
  short*    h1b   = (short*)(ws + OFF_H1);
  short*    h2b   = (short*)(ws + OFF_H2);
  float*    h2f32 = (float*)(ws + OFF_H2F);
  unsigned* bar   = (unsigned*)(ws + OFF_BAR);
  short*    xb    = (short*)(ws + OFF_XB);

  hipMemsetAsync(d_ws, 0, OFF_XB, stream);   // h-state, h2f32, barrier
  conv_x<<<dim3(8192), dim3(WGS), 0, stream>>>(x, xb);
  hipFuncSetAttribute(reinterpret_cast<const void*>(lstm2),
                      hipFuncAttributeMaxDynamicSharedMemorySize, 131584);
  lstm2<<<dim3(NBLK), dim3(WGS), 131584, stream>>>(
      xb, Wih1, Whh1, bih1, bhh1, Wih2, Whh2, bih2, bhh2,
      h1b, h2b, h2f32, bar);
  final_linear<<<dim3(Bb), dim3(256), 0, stream>>>(h2f32, Wlin, blin, out);
}